// Round 12
// baseline (579.257 us; speedup 1.0000x reference)
//
#include <hip/hip_runtime.h>

typedef unsigned short u16;
typedef unsigned int u32;
typedef __attribute__((ext_vector_type(8))) short s16x8;   // 8 bf16 (4 VGPRs)
typedef __attribute__((ext_vector_type(4))) float f32x4;

__device__ __forceinline__ float bf2f(u16 u) { return __uint_as_float(((u32)u) << 16); }
__device__ __forceinline__ u16 f2bf(float f) {
    u32 b = __float_as_uint(f);
    b += 0x7fffu + ((b >> 16) & 1u);
    return (u16)(b >> 16);
}

__global__ void probe_mark(float* __restrict__ out, int n, float val) {
    int i = blockIdx.x * blockDim.x + threadIdx.x;
    if (i < n) out[i] = val;
}

// ---------------- merged prep: zero + wt convert + att proj + x->bf16 convert ----------------
struct PrepX { const float* x[4]; int rows[4]; int blks[4]; u16* xb[4]; };

__global__ void k_prep_all(const float* __restrict__ Ws, const float* __restrict__ W_res,
                           const float* __restrict__ att_src, const float* __restrict__ att_dst,
                           const float* __restrict__ biases,
                           u32* __restrict__ cnt, int zc, int nzb, u16* __restrict__ wt,
                           float* __restrict__ w_d_all, float* __restrict__ w_s_cat,
                           float* __restrict__ bias_sum, PrepX PX) {
    int b = blockIdx.x;
    if (b < nzb) {
        int i = b * 256 + threadIdx.x;
        if (i < zc) cnt[i] = 0u;
        return;
    }
    b -= nzb;
    if (b < 768) {                      // 768*256 == 6*256*128 exactly
        int i = b * 256 + threadIdx.x;
        int k = i & 127;
        int c = (i >> 7) & 255;
        int w = i >> 15;
        float v = (w < 5) ? Ws[(size_t)w * 32768 + k * 256 + c] : W_res[k * 256 + c];
        wt[i] = f2bf(v);
        return;
    }
    b -= 768;
    if (b < 6) {
        if (b < 5) {
            int k = threadIdx.x;
            if (k >= 128) return;
            const float* Wr = Ws + (size_t)b * 128 * 256 + (size_t)k * 256;
            for (int h = 0; h < 4; ++h) {
                float ss = 0.f, sd = 0.f;
                for (int c = 0; c < 64; ++c) {
                    float w = Wr[h * 64 + c];
                    ss += w * att_src[(b * 4 + h) * 64 + c];
                    sd += w * att_dst[(b * 4 + h) * 64 + c];
                }
                w_d_all[k * 20 + b * 4 + h] = sd;
                w_s_cat[b * 512 + k * 4 + h] = ss;
            }
        } else if (threadIdx.x < 256) {
            float s = 0.f;
            for (int r = 0; r < 5; ++r) s += biases[r * 256 + threadIdx.x];
            bias_sum[threadIdx.x] = s;
        }
        return;
    }
    b -= 6;
    // xb convert: 256 threads x 8 elems = 2048 fp32/block per sub-region
#pragma unroll
    for (int a = 0; a < 4; ++a) {
        if (b < PX.blks[a]) {
            int elem = b * 2048 + threadIdx.x * 8;
            if (elem < PX.rows[a] * 128) {          // elem%8==0, tot%8==0 -> full chunk
                const float4* src = (const float4*)(PX.x[a] + elem);
                float4 v0 = src[0], v1 = src[1];
                u32 w0 = ((u32)f2bf(v0.y) << 16) | f2bf(v0.x);
                u32 w1 = ((u32)f2bf(v0.w) << 16) | f2bf(v0.z);
                u32 w2 = ((u32)f2bf(v1.y) << 16) | f2bf(v1.x);
                u32 w3 = ((u32)f2bf(v1.w) << 16) | f2bf(v1.z);
                *(uint4*)(PX.xb[a] + elem) = make_uint4(w0, w1, w2, w3);
            }
            return;
        }
        b -= PX.blks[a];
    }
}

// ---------------- merged skinny GEMMs v2: thread = (row, 4-col group), float4 loads ----------
struct SDesc { const float* A; const float* W; float* out; int N; int Kout; int groups; int start; };
struct STab { SDesc d[6]; int total; };

__global__ void skinny_all(STab T) {
    int idx = blockIdx.x * blockDim.x + threadIdx.x;
    if (idx >= T.total) return;
    int mi = 0;
#pragma unroll
    for (int i = 1; i < 6; ++i) if (idx >= T.d[i].start) mi = i;
    SDesc d = T.d[mi];
    int local = idx - d.start;
    int row = local / d.groups, g = local - row * d.groups;
    const float* a = d.A + (size_t)row * 128;
    const float* w = d.W + g * 4;
    int Kout = d.Kout;
    float s0 = 0.f, s1 = 0.f, s2 = 0.f, s3 = 0.f;
    for (int k = 0; k < 128; k += 4) {
        float4 av = *(const float4*)(a + k);
        float4 w0 = *(const float4*)(w + (size_t)(k + 0) * Kout);
        float4 w1 = *(const float4*)(w + (size_t)(k + 1) * Kout);
        float4 w2 = *(const float4*)(w + (size_t)(k + 2) * Kout);
        float4 w3 = *(const float4*)(w + (size_t)(k + 3) * Kout);
        s0 += av.x * w0.x + av.y * w1.x + av.z * w2.x + av.w * w3.x;
        s1 += av.x * w0.y + av.y * w1.y + av.z * w2.y + av.w * w3.y;
        s2 += av.x * w0.z + av.y * w1.z + av.z * w2.z + av.w * w3.z;
        s3 += av.x * w0.w + av.y * w1.w + av.z * w2.w + av.w * w3.w;
    }
    float* o = d.out + (size_t)row * Kout + g * 4;
    *(float4*)o = make_float4(s0, s1, s2, s3);
}

// ---------------- merged MFMA GEMMs (LDS; col-strip loop inside, A staged once) -------------
struct GDesc { const u16* A; u16* C; int wslice; int N; int start; };
struct GTab { GDesc d[6]; };

__global__ __launch_bounds__(256) void gemm_all(GTab T, const u16* __restrict__ wt) {
    __shared__ __align__(16) u16 sA[64][136];
    __shared__ __align__(16) u16 sB[64][136];
    int bx = blockIdx.x;
    int mi = 0;
#pragma unroll
    for (int i = 1; i < 6; ++i) if (bx >= T.d[i].start) mi = i;
    GDesc d = T.d[mi];
    int R0 = (bx - d.start) * 64;
    int t = threadIdx.x;
    int r = t >> 2, seg = (t & 3) * 32;
    {   // stage A once (bf16 direct)
        uint4 a0, a1, a2, a3;
        if (R0 + r < d.N) {
            const uint4* pa = (const uint4*)(d.A + (size_t)(R0 + r) * 128 + seg);
            a0 = pa[0]; a1 = pa[1]; a2 = pa[2]; a3 = pa[3];
        } else {
            a0 = a1 = a2 = a3 = make_uint4(0, 0, 0, 0);
        }
        uint4* qd = (uint4*)&sA[r][seg];
        qd[0] = a0; qd[1] = a1; qd[2] = a2; qd[3] = a3;
    }
    int wave = t >> 6, lane = t & 63;
    int quad = lane >> 4, m = lane & 15;
    const u16* aRow = &sA[wave * 16 + m][0];
    const u16* wbase = wt + (size_t)d.wslice * 32768;

    for (int y = 0; y < 4; ++y) {
        int c0 = y * 64;
        // prefetch B strip into regs (overlaps previous strip's MFMA)
        const uint4* pb = (const uint4*)(wbase + (size_t)(c0 + r) * 128 + seg);
        uint4 b0 = pb[0], b1 = pb[1], b2 = pb[2], b3 = pb[3];
        __syncthreads();                      // y>0: all waves done reading sB; y=0: no-op cost
        uint4* qb = (uint4*)&sB[r][seg];
        qb[0] = b0; qb[1] = b1; qb[2] = b2; qb[3] = b3;
        __syncthreads();                      // sB (and sA on y=0) visible

        f32x4 acc[4] = {};
#pragma unroll
        for (int k0 = 0; k0 < 128; k0 += 32) {
            s16x8 af = *(const s16x8*)(aRow + k0 + quad * 8);
#pragma unroll
            for (int ct = 0; ct < 4; ++ct) {
                s16x8 bf = *(const s16x8*)(&sB[ct * 16 + m][k0 + quad * 8]);
                acc[ct] = __builtin_amdgcn_mfma_f32_16x16x32_bf16(af, bf, acc[ct], 0, 0, 0);
            }
        }
        // C/D: col = lane&15, row = (lane>>4)*4 + reg
#pragma unroll
        for (int ct = 0; ct < 4; ++ct) {
#pragma unroll
            for (int i = 0; i < 4; ++i) {
                int row = R0 + wave * 16 + quad * 4 + i;
                if (row < d.N) d.C[(size_t)row * 256 + c0 + ct * 16 + m] = f2bf(acc[ct][i]);
            }
        }
    }
}

// ---------------- (row,rel)-segmented CSR build over all 5 relations ----------------
struct EdgeP { const int* src[5]; const int* dst[5]; int base[5]; };

__global__ void k_count(EdgeP P, u32* __restrict__ cnt, int E) {
    int r = blockIdx.y;
    int e = blockIdx.x * blockDim.x + threadIdx.x;
    if (e >= E) return;
    atomicAdd(cnt + (size_t)P.dst[r][e] * 5 + r, 1u);
}

__global__ void k_scan1(const u32* __restrict__ cnt, u32* __restrict__ off,
                        u32* __restrict__ bsum, int nblk) {
    int b = blockIdx.x, t = threadIdx.x;
    size_t base = (size_t)b * 1024 + t * 4;
    u32 v0 = cnt[base], v1 = cnt[base + 1], v2 = cnt[base + 2], v3 = cnt[base + 3];
    u32 tsum = v0 + v1 + v2 + v3;
    __shared__ u32 s[256];
    u32 x = tsum;
    s[t] = x; __syncthreads();
    for (int ofs = 1; ofs < 256; ofs <<= 1) {
        u32 y = (t >= ofs) ? s[t - ofs] : 0u;
        __syncthreads();
        x += y; s[t] = x;
        __syncthreads();
    }
    u32 ex = x - tsum;
    off[base] = ex; off[base + 1] = ex + v0; off[base + 2] = ex + v0 + v1; off[base + 3] = ex + v0 + v1 + v2;
    if (t == 255) bsum[b] = x;
}

// merged scan2+scan3: each block sums bsum[0..b) itself (bsum is L2-hot, ~489 u32)
__global__ void k_scan23(u32* __restrict__ off, const u32* __restrict__ bsum, int nblk) {
    int b = blockIdx.x, t = threadIdx.x;   // 256 threads
    __shared__ u32 s[256];
    u32 part = 0;
    for (int i = t; i < b; i += 256) part += bsum[i];
    s[t] = part; __syncthreads();
    for (int ofs = 128; ofs; ofs >>= 1) {
        if (t < ofs) s[t] += s[t + ofs];
        __syncthreads();
    }
    u32 add = s[0];
    size_t base = (size_t)b * 1024 + t * 4;
    off[base] += add; off[base + 1] += add; off[base + 2] += add; off[base + 3] += add;
}

__global__ void k_fill(EdgeP P, const u32* __restrict__ off, u32* __restrict__ cur,
                       u32* __restrict__ epay, int E) {
    int r = blockIdx.y;
    int e = blockIdx.x * blockDim.x + threadIdx.x;
    if (e >= E) return;
    int d = P.dst[r][e];
    size_t slot = (size_t)d * 5 + r;
    u32 pos = off[slot] + atomicAdd(cur + slot, 1u);
    epay[pos] = (u32)(P.base[r] + P.src[r][e]);
}

// ---------------- fused gather — R9/R11 version, row-range split for profiling -----------
// Identical code/access pattern; launched as 4 row-range chunks (~41us each) so the
// rocprof top-5 can surface the #2..#N kernels that 162us monolithic gather masked.
__global__ __launch_bounds__(512) void k_gather(
        const u32* __restrict__ offs, const u32* __restrict__ epay,
        const float* __restrict__ as_h,   // as_cat: [gsrc][4 heads]
        const float* __restrict__ a_d,    // [row][rel*4+h]
        const u16* __restrict__ hs, const u16* __restrict__ resb,
        const float* __restrict__ bias_sum,
        const float* __restrict__ gamma, const float* __restrict__ beta,
        float* __restrict__ out, int row0, int rowEnd) {
    int row = row0 + blockIdx.x * 8 + (threadIdx.x >> 6);
    int lane = threadIdx.x & 63;
    if (row >= rowEnd) return;

    // hoisted epilogue loads — hide under the gather
    ushort4 rr = *(const ushort4*)(resb + (size_t)row * 256 + lane * 4);
    float4 bb = *(const float4*)(bias_sum + lane * 4);
    int c = lane * 4;
    float4 g = *(const float4*)(gamma + c);
    float4 be = *(const float4*)(beta + c);

    int hd = lane >> 4;                        // this lane's head (0..3)
    u32 hoff = (u32)(lane << 2);               // u16-elem offset within an hs row

    const float* adb = a_d + (size_t)row * 20 + hd;
    float adx[5] = { adb[0], adb[4], adb[8], adb[12], adb[16] };

    const u32* op = offs + (size_t)row * 5;
    u32 o[6];
#pragma unroll
    for (int i = 0; i < 6; ++i) o[i] = op[i];
    u32 deg = o[5] - o[0];

    // cooperative payload preload: lane L holds epay[o0+L] (covers rows with deg<=64)
    u32 pv = 0;
    if (deg) {
        u32 li = (u32)lane < deg ? (u32)lane : 0u;
        pv = epay[o[0] + li];
    }

    float a0 = 0.f, a1 = 0.f, a2 = 0.f, a3 = 0.f;
#pragma unroll
    for (int r = 0; r < 5; ++r) {              // rel is a compile-time constant
        float adr = adx[r];
        float n0 = 0.f, n1 = 0.f, n2 = 0.f, n3 = 0.f, dsum = 0.f;
        for (u32 e = o[r]; e < o[r + 1]; ++e) {
            u32 i = e - o[0];
            u32 p;
            if (i < 64u) p = __shfl(pv, (int)i);   // wave-uniform condition
            else         p = epay[e];
            float x = as_h[p * 4 + (u32)hd] + adr;
            x = x > 0.f ? x : 0.2f * x;
            float w = __expf(x);
            dsum += w;
            ushort4 hv = *(const ushort4*)(hs + ((size_t)p << 8) + hoff);
            n0 += w * bf2f(hv.x); n1 += w * bf2f(hv.y);
            n2 += w * bf2f(hv.z); n3 += w * bf2f(hv.w);
        }
        float iv = 1.f / (dsum + 1e-16f);      // empty segment: contributes 0, safe
        a0 += n0 * iv; a1 += n1 * iv; a2 += n2 * iv; a3 += n3 * iv;
    }

    float h0 = fmaxf(a0 + bf2f(rr.x) + bb.x, 0.f);
    float h1 = fmaxf(a1 + bf2f(rr.y) + bb.y, 0.f);
    float h2 = fmaxf(a2 + bf2f(rr.z) + bb.z, 0.f);
    float h3 = fmaxf(a3 + bf2f(rr.w) + bb.w, 0.f);
    float s = h0 + h1 + h2 + h3;
    float s2 = h0 * h0 + h1 * h1 + h2 * h2 + h3 * h3;
    for (int o2 = 32; o2; o2 >>= 1) {
        s += __shfl_xor(s, o2);
        s2 += __shfl_xor(s2, o2);
    }
    float mu = s * (1.f / 256.f);
    float var = s2 * (1.f / 256.f) - mu * mu;
    float rs = rsqrtf(var + 1e-5f);
    float4 o4;
    o4.x = (h0 - mu) * rs * g.x + be.x;
    o4.y = (h1 - mu) * rs * g.y + be.y;
    o4.z = (h2 - mu) * rs * g.z + be.z;
    o4.w = (h3 - mu) * rs * g.w + be.w;
    *(float4*)(out + (size_t)row * 256 + c) = o4;
}

// ---------------------------------------------------------------------------
static size_t align256(size_t x) { return (x + 255) & ~(size_t)255; }

extern "C" void kernel_launch(void* const* d_in, const int* in_sizes, int n_in,
                              void* d_out, int out_size, void* d_ws, size_t ws_size,
                              hipStream_t stream) {
    float* out = (float*)d_out;

    int NJ = in_sizes[0] / 128, NS = in_sizes[1] / 128, NM = in_sizes[2] / 128, NR = in_sizes[3] / 128;
    int E = in_sizes[4];
    bool cfg_ok = (n_in >= 21) && (out_size == NJ * 256)
        && (in_sizes[14] == 5 * 128 * 256) && (in_sizes[18] == 128 * 256)
        && (in_sizes[19] == 256) && (in_sizes[20] == 256);
    if (!cfg_ok) { probe_mark<<<8, 256, 0, stream>>>(out, 2048, 1000000.0f); return; }

    const float* x_job = (const float*)d_in[0];
    const float* x_st  = (const float*)d_in[1];
    const float* x_ma  = (const float*)d_in[2];
    const float* x_ro  = (const float*)d_in[3];
    EdgeP EP;
    EP.src[0] = (const int*)d_in[4];  EP.dst[0] = (const int*)d_in[5];
    EP.src[1] = (const int*)d_in[6];  EP.dst[1] = (const int*)d_in[7];
    EP.src[2] = (const int*)d_in[8];  EP.dst[2] = (const int*)d_in[9];
    EP.src[3] = (const int*)d_in[10]; EP.dst[3] = (const int*)d_in[11];
    EP.src[4] = (const int*)d_in[12]; EP.dst[4] = (const int*)d_in[13];
    EP.base[0] = 0; EP.base[1] = NS; EP.base[2] = 2 * NS;
    EP.base[3] = 2 * NS + NM; EP.base[4] = 2 * NS + 2 * NM;
    const float* Ws      = (const float*)d_in[14];
    const float* att_src = (const float*)d_in[15];
    const float* att_dst = (const float*)d_in[16];
    const float* biases  = (const float*)d_in[17];
    const float* W_res   = (const float*)d_in[18];
    const float* gamma   = (const float*)d_in[19];
    const float* beta    = (const float*)d_in[20];

    int nseg = 5 * NJ;
    int nblk = (nseg + 1023) / 1024;
    int NPAD = nblk * 1024;
    int TOT = 2 * NS + 2 * NM + NR;        // concatenated source-node count (hs_cat)
    int TOTX = NJ + NS + NM + NR;          // distinct x rows (xb)

    // --- workspace layout ---
    char* base = (char*)d_ws;
    size_t ob = 0;
    float*  w_d_all  = (float*)(base + ob);  ob += align256(128 * 20 * 4);
    float*  w_s_cat  = (float*)(base + ob);  ob += align256(5 * 128 * 4 * 4);
    float*  bias_sum = (float*)(base + ob);  ob += align256(256 * 4);
    float*  a_d      = (float*)(base + ob);  ob += align256((size_t)NJ * 20 * 4);
    float*  as_cat   = (float*)(base + ob);  ob += align256((size_t)TOT * 4 * 4);
    u16*    wt       = (u16*)(base + ob);    ob += align256((size_t)6 * 256 * 128 * 2);
    u16*    xb       = (u16*)(base + ob);    ob += align256((size_t)TOTX * 128 * 2);
    u16*    resb     = (u16*)(base + ob);    ob += align256((size_t)NJ * 256 * 2);
    u16*    hs_cat   = (u16*)(base + ob);    ob += align256((size_t)TOT * 256 * 2);
    u32*    cnt      = (u32*)(base + ob);    ob += align256((size_t)NPAD * 4);
    u32*    cur      = (u32*)(base + ob);    ob += align256((size_t)NPAD * 4);
    u32*    offs     = (u32*)(base + ob);    ob += align256((size_t)NPAD * 4);
    u32*    bsum     = (u32*)(base + ob);    ob += align256((size_t)nblk * 4);
    u32*    epay     = (u32*)(base + ob);    ob += align256((size_t)5 * E * 4);

    if (ws_size < ob) { probe_mark<<<8, 256, 0, stream>>>(out, 2048, 500000.0f); return; }

    // --- merged prep (zero cnt+cur, wt, att proj, x->bf16) ---
    int zc = 2 * NPAD;
    int nzb = (zc + 255) / 256;
    PrepX PX;
    PX.x[0] = x_job; PX.x[1] = x_st; PX.x[2] = x_ma; PX.x[3] = x_ro;
    PX.rows[0] = NJ; PX.rows[1] = NS; PX.rows[2] = NM; PX.rows[3] = NR;
    u16* xb_job = xb;
    u16* xb_st  = xb + (size_t)NJ * 128;
    u16* xb_ma  = xb + (size_t)(NJ + NS) * 128;
    u16* xb_ro  = xb + (size_t)(NJ + NS + NM) * 128;
    PX.xb[0] = xb_job; PX.xb[1] = xb_st; PX.xb[2] = xb_ma; PX.xb[3] = xb_ro;
    int nxb = 0;
    for (int a = 0; a < 4; ++a) { PX.blks[a] = (PX.rows[a] * 128 + 2047) / 2048; nxb += PX.blks[a]; }
    k_prep_all<<<nzb + 768 + 6 + nxb, 256, 0, stream>>>(Ws, W_res, att_src, att_dst, biases,
                                                        cnt, zc, nzb, wt,
                                                        w_d_all, w_s_cat, bias_sum, PX);

    // --- merged skinny GEMMs v2 (thread = row x 4-col group) ---
    STab ST;
    int st = 0;
    ST.d[0] = {x_job, w_d_all,           a_d,                             NJ, 20, 5, st}; st += NJ * 5;
    ST.d[1] = {x_st,  w_s_cat + 0 * 512, as_cat + (size_t)EP.base[0] * 4, NS, 4, 1, st}; st += NS;
    ST.d[2] = {x_st,  w_s_cat + 1 * 512, as_cat + (size_t)EP.base[1] * 4, NS, 4, 1, st}; st += NS;
    ST.d[3] = {x_ma,  w_s_cat + 2 * 512, as_cat + (size_t)EP.base[2] * 4, NM, 4, 1, st}; st += NM;
    ST.d[4] = {x_ma,  w_s_cat + 3 * 512, as_cat + (size_t)EP.base[3] * 4, NM, 4, 1, st}; st += NM;
    ST.d[5] = {x_ro,  w_s_cat + 4 * 512, as_cat + (size_t)EP.base[4] * 4, NR, 4, 1, st}; st += NR;
    ST.total = st;
    skinny_all<<<(ST.total + 255) / 256, 256, 0, stream>>>(ST);

    // --- merged MFMA GEMMs (1-D grid; strip loop inside, A staged once) ---
    int tJ = (NJ + 63) / 64, tS = (NS + 63) / 64, tM = (NM + 63) / 64, tR = (NR + 63) / 64;
    GTab GT;
    int gs = 0;
    GT.d[0] = {xb_job, resb,                              5, NJ, gs}; gs += tJ;
    GT.d[1] = {xb_st,  hs_cat + (size_t)EP.base[0] * 256, 0, NS, gs}; gs += tS;
    GT.d[2] = {xb_st,  hs_cat + (size_t)EP.base[1] * 256, 1, NS, gs}; gs += tS;
    GT.d[3] = {xb_ma,  hs_cat + (size_t)EP.base[2] * 256, 2, NM, gs}; gs += tM;
    GT.d[4] = {xb_ma,  hs_cat + (size_t)EP.base[3] * 256, 3, NM, gs}; gs += tM;
    GT.d[5] = {xb_ro,  hs_cat + (size_t)EP.base[4] * 256, 4, NR, gs}; gs += tR;
    gemm_all<<<gs, 256, 0, stream>>>(GT, wt);

    // --- (row,rel)-segmented CSR build (scan-based) ---
    k_count<<<dim3((E + 255) / 256, 5), 256, 0, stream>>>(EP, cnt, E);
    k_scan1<<<nblk, 256, 0, stream>>>(cnt, offs, bsum, nblk);
    k_scan23<<<nblk, 256, 0, stream>>>(offs, bsum, nblk);
    k_fill<<<dim3((E + 255) / 256, 5), 256, 0, stream>>>(EP, offs, cur, epay, E);

    // --- fused gather, split into 4 row-range chunks (profiling visibility; same work) ---
    int qr = (NJ + 3) / 4;
    for (int q = 0; q < 4; ++q) {
        int r0 = q * qr;
        int r1 = (q == 3) ? NJ : (q + 1) * qr;
        if (r1 > r0)
            k_gather<<<((r1 - r0) + 7) / 8, 512, 0, stream>>>(offs, epay, as_cat,
                                                              a_d, hs_cat, resb, bias_sum,
                                                              gamma, beta, out, r0, r1);
    }
}

// Round 13
// 529.011 us; speedup vs baseline: 1.0950x; 1.0950x over previous
//
#include <hip/hip_runtime.h>

typedef unsigned short u16;
typedef unsigned int u32;
typedef __attribute__((ext_vector_type(8))) short s16x8;   // 8 bf16 (4 VGPRs)
typedef __attribute__((ext_vector_type(4))) float f32x4;

__device__ __forceinline__ float bf2f(u16 u) { return __uint_as_float(((u32)u) << 16); }
__device__ __forceinline__ u16 f2bf(float f) {
    u32 b = __float_as_uint(f);
    b += 0x7fffu + ((b >> 16) & 1u);
    return (u16)(b >> 16);
}

__global__ void probe_mark(float* __restrict__ out, int n, float val) {
    int i = blockIdx.x * blockDim.x + threadIdx.x;
    if (i < n) out[i] = val;
}

// ---------------- merged prep: zero cnt + wt convert + att proj + x->bf16 convert ------------
struct PrepX { const float* x[4]; int rows[4]; int blks[4]; u16* xb[4]; };

__global__ void k_prep_all(const float* __restrict__ Ws, const float* __restrict__ W_res,
                           const float* __restrict__ att_src, const float* __restrict__ att_dst,
                           const float* __restrict__ biases,
                           u32* __restrict__ cnt, int zc, int nzb, u16* __restrict__ wt,
                           float* __restrict__ w_d_all, float* __restrict__ w_s_cat,
                           float* __restrict__ bias_sum, PrepX PX) {
    int b = blockIdx.x;
    if (b < nzb) {
        int i = b * 256 + threadIdx.x;
        if (i < zc) cnt[i] = 0u;
        return;
    }
    b -= nzb;
    if (b < 768) {                      // 768*256 == 6*256*128 exactly
        int i = b * 256 + threadIdx.x;
        int k = i & 127;
        int c = (i >> 7) & 255;
        int w = i >> 15;
        float v = (w < 5) ? Ws[(size_t)w * 32768 + k * 256 + c] : W_res[k * 256 + c];
        wt[i] = f2bf(v);
        return;
    }
    b -= 768;
    if (b < 6) {
        if (b < 5) {
            int k = threadIdx.x;
            if (k >= 128) return;
            const float* Wr = Ws + (size_t)b * 128 * 256 + (size_t)k * 256;
            for (int h = 0; h < 4; ++h) {
                float ss = 0.f, sd = 0.f;
                for (int c = 0; c < 64; ++c) {
                    float w = Wr[h * 64 + c];
                    ss += w * att_src[(b * 4 + h) * 64 + c];
                    sd += w * att_dst[(b * 4 + h) * 64 + c];
                }
                w_d_all[k * 20 + b * 4 + h] = sd;
                w_s_cat[b * 512 + k * 4 + h] = ss;
            }
        } else if (threadIdx.x < 256) {
            float s = 0.f;
            for (int r = 0; r < 5; ++r) s += biases[r * 256 + threadIdx.x];
            bias_sum[threadIdx.x] = s;
        }
        return;
    }
    b -= 6;
    // xb convert: 256 threads x 8 elems = 2048 fp32/block per sub-region
#pragma unroll
    for (int a = 0; a < 4; ++a) {
        if (b < PX.blks[a]) {
            int elem = b * 2048 + threadIdx.x * 8;
            if (elem < PX.rows[a] * 128) {          // elem%8==0, tot%8==0 -> full chunk
                const float4* src = (const float4*)(PX.x[a] + elem);
                float4 v0 = src[0], v1 = src[1];
                u32 w0 = ((u32)f2bf(v0.y) << 16) | f2bf(v0.x);
                u32 w1 = ((u32)f2bf(v0.w) << 16) | f2bf(v0.z);
                u32 w2 = ((u32)f2bf(v1.y) << 16) | f2bf(v1.x);
                u32 w3 = ((u32)f2bf(v1.w) << 16) | f2bf(v1.z);
                *(uint4*)(PX.xb[a] + elem) = make_uint4(w0, w1, w2, w3);
            }
            return;
        }
        b -= PX.blks[a];
    }
}

// ---------------- merged skinny GEMMs v2: thread = (row, 4-col group), float4 loads ----------
struct SDesc { const float* A; const float* W; float* out; int N; int Kout; int groups; int start; };
struct STab { SDesc d[6]; int total; };

__global__ void skinny_all(STab T) {
    int idx = blockIdx.x * blockDim.x + threadIdx.x;
    if (idx >= T.total) return;
    int mi = 0;
#pragma unroll
    for (int i = 1; i < 6; ++i) if (idx >= T.d[i].start) mi = i;
    SDesc d = T.d[mi];
    int local = idx - d.start;
    int row = local / d.groups, g = local - row * d.groups;
    const float* a = d.A + (size_t)row * 128;
    const float* w = d.W + g * 4;
    int Kout = d.Kout;
    float s0 = 0.f, s1 = 0.f, s2 = 0.f, s3 = 0.f;
    for (int k = 0; k < 128; k += 4) {
        float4 av = *(const float4*)(a + k);
        float4 w0 = *(const float4*)(w + (size_t)(k + 0) * Kout);
        float4 w1 = *(const float4*)(w + (size_t)(k + 1) * Kout);
        float4 w2 = *(const float4*)(w + (size_t)(k + 2) * Kout);
        float4 w3 = *(const float4*)(w + (size_t)(k + 3) * Kout);
        s0 += av.x * w0.x + av.y * w1.x + av.z * w2.x + av.w * w3.x;
        s1 += av.x * w0.y + av.y * w1.y + av.z * w2.y + av.w * w3.y;
        s2 += av.x * w0.z + av.y * w1.z + av.z * w2.z + av.w * w3.z;
        s3 += av.x * w0.w + av.y * w1.w + av.z * w2.w + av.w * w3.w;
    }
    float* o = d.out + (size_t)row * Kout + g * 4;
    *(float4*)o = make_float4(s0, s1, s2, s3);
}

// ---------------- merged MFMA GEMMs (LDS; col-strip loop inside, A staged once) -------------
struct GDesc { const u16* A; u16* C; int wslice; int N; int start; };
struct GTab { GDesc d[6]; };

__global__ __launch_bounds__(256) void gemm_all(GTab T, const u16* __restrict__ wt) {
    __shared__ __align__(16) u16 sA[64][136];
    __shared__ __align__(16) u16 sB[64][136];
    int bx = blockIdx.x;
    int mi = 0;
#pragma unroll
    for (int i = 1; i < 6; ++i) if (bx >= T.d[i].start) mi = i;
    GDesc d = T.d[mi];
    int R0 = (bx - d.start) * 64;
    int t = threadIdx.x;
    int r = t >> 2, seg = (t & 3) * 32;
    {   // stage A once (bf16 direct)
        uint4 a0, a1, a2, a3;
        if (R0 + r < d.N) {
            const uint4* pa = (const uint4*)(d.A + (size_t)(R0 + r) * 128 + seg);
            a0 = pa[0]; a1 = pa[1]; a2 = pa[2]; a3 = pa[3];
        } else {
            a0 = a1 = a2 = a3 = make_uint4(0, 0, 0, 0);
        }
        uint4* qd = (uint4*)&sA[r][seg];
        qd[0] = a0; qd[1] = a1; qd[2] = a2; qd[3] = a3;
    }
    int wave = t >> 6, lane = t & 63;
    int quad = lane >> 4, m = lane & 15;
    const u16* aRow = &sA[wave * 16 + m][0];
    const u16* wbase = wt + (size_t)d.wslice * 32768;

    for (int y = 0; y < 4; ++y) {
        int c0 = y * 64;
        // prefetch B strip into regs (overlaps previous strip's MFMA)
        const uint4* pb = (const uint4*)(wbase + (size_t)(c0 + r) * 128 + seg);
        uint4 b0 = pb[0], b1 = pb[1], b2 = pb[2], b3 = pb[3];
        __syncthreads();                      // y>0: all waves done reading sB; y=0: no-op cost
        uint4* qb = (uint4*)&sB[r][seg];
        qb[0] = b0; qb[1] = b1; qb[2] = b2; qb[3] = b3;
        __syncthreads();                      // sB (and sA on y=0) visible

        f32x4 acc[4] = {};
#pragma unroll
        for (int k0 = 0; k0 < 128; k0 += 32) {
            s16x8 af = *(const s16x8*)(aRow + k0 + quad * 8);
#pragma unroll
            for (int ct = 0; ct < 4; ++ct) {
                s16x8 bf = *(const s16x8*)(&sB[ct * 16 + m][k0 + quad * 8]);
                acc[ct] = __builtin_amdgcn_mfma_f32_16x16x32_bf16(af, bf, acc[ct], 0, 0, 0);
            }
        }
        // C/D: col = lane&15, row = (lane>>4)*4 + reg
#pragma unroll
        for (int ct = 0; ct < 4; ++ct) {
#pragma unroll
            for (int i = 0; i < 4; ++i) {
                int row = R0 + wave * 16 + quad * 4 + i;
                if (row < d.N) d.C[(size_t)row * 256 + c0 + ct * 16 + m] = f2bf(acc[ct][i]);
            }
        }
    }
}

// ---------------- (row,rel)-segmented CSR build over all 5 relations ----------------
// R12 PMC: k_fill 68us, VALUBusy 0.6% -> pure latency on the chain {random offs load ->
// random atomicAdd(cur) -> scatter write}. Fix: k_count RECORDS each edge's intra-bucket
// position (the atomicAdd return it was discarding) into epos (coalesced). k_fill then
// needs NO atomics: pos = offs[slot] + epos[e]. cur[] and its zeroing disappear.
struct EdgeP { const int* src[5]; const int* dst[5]; int base[5]; };

__global__ void k_count(EdgeP P, u32* __restrict__ cnt, u32* __restrict__ epos, int E) {
    int r = blockIdx.y;
    int e = blockIdx.x * blockDim.x + threadIdx.x;
    if (e >= E) return;
    u32 c = atomicAdd(cnt + (size_t)P.dst[r][e] * 5 + r, 1u);
    epos[(size_t)r * E + e] = c;
}

__global__ void k_scan1(const u32* __restrict__ cnt, u32* __restrict__ off,
                        u32* __restrict__ bsum, int nblk) {
    int b = blockIdx.x, t = threadIdx.x;
    size_t base = (size_t)b * 1024 + t * 4;
    u32 v0 = cnt[base], v1 = cnt[base + 1], v2 = cnt[base + 2], v3 = cnt[base + 3];
    u32 tsum = v0 + v1 + v2 + v3;
    __shared__ u32 s[256];
    u32 x = tsum;
    s[t] = x; __syncthreads();
    for (int ofs = 1; ofs < 256; ofs <<= 1) {
        u32 y = (t >= ofs) ? s[t - ofs] : 0u;
        __syncthreads();
        x += y; s[t] = x;
        __syncthreads();
    }
    u32 ex = x - tsum;
    off[base] = ex; off[base + 1] = ex + v0; off[base + 2] = ex + v0 + v1; off[base + 3] = ex + v0 + v1 + v2;
    if (t == 255) bsum[b] = x;
}

// merged scan2+scan3: each block sums bsum[0..b) itself (bsum is L2-hot, ~489 u32)
__global__ void k_scan23(u32* __restrict__ off, const u32* __restrict__ bsum, int nblk) {
    int b = blockIdx.x, t = threadIdx.x;   // 256 threads
    __shared__ u32 s[256];
    u32 part = 0;
    for (int i = t; i < b; i += 256) part += bsum[i];
    s[t] = part; __syncthreads();
    for (int ofs = 128; ofs; ofs >>= 1) {
        if (t < ofs) s[t] += s[t + ofs];
        __syncthreads();
    }
    u32 add = s[0];
    size_t base = (size_t)b * 1024 + t * 4;
    off[base] += add; off[base + 1] += add; off[base + 2] += add; off[base + 3] += add;
}

__global__ void k_fill(EdgeP P, const u32* __restrict__ off, const u32* __restrict__ epos,
                       u32* __restrict__ epay, int E) {
    int r = blockIdx.y;
    int e = blockIdx.x * blockDim.x + threadIdx.x;
    if (e >= E) return;
    int d = P.dst[r][e];
    u32 pos = off[(size_t)d * 5 + r] + epos[(size_t)r * E + e];
    epay[pos] = (u32)(P.base[r] + P.src[r][e]);
}

// ---------------- fused gather — R9/R11 version (best measured ~162us), FROZEN -----------
__global__ __launch_bounds__(512) void k_gather(
        const u32* __restrict__ offs, const u32* __restrict__ epay,
        const float* __restrict__ as_h,   // as_cat: [gsrc][4 heads]
        const float* __restrict__ a_d,    // [row][rel*4+h]
        const u16* __restrict__ hs, const u16* __restrict__ resb,
        const float* __restrict__ bias_sum,
        const float* __restrict__ gamma, const float* __restrict__ beta,
        float* __restrict__ out, int NJ) {
    int row = blockIdx.x * 8 + (threadIdx.x >> 6);
    int lane = threadIdx.x & 63;
    if (row >= NJ) return;

    // hoisted epilogue loads — hide under the gather
    ushort4 rr = *(const ushort4*)(resb + (size_t)row * 256 + lane * 4);
    float4 bb = *(const float4*)(bias_sum + lane * 4);
    int c = lane * 4;
    float4 g = *(const float4*)(gamma + c);
    float4 be = *(const float4*)(beta + c);

    int hd = lane >> 4;                        // this lane's head (0..3)
    u32 hoff = (u32)(lane << 2);               // u16-elem offset within an hs row

    const float* adb = a_d + (size_t)row * 20 + hd;
    float adx[5] = { adb[0], adb[4], adb[8], adb[12], adb[16] };

    const u32* op = offs + (size_t)row * 5;
    u32 o[6];
#pragma unroll
    for (int i = 0; i < 6; ++i) o[i] = op[i];
    u32 deg = o[5] - o[0];

    // cooperative payload preload: lane L holds epay[o0+L] (covers rows with deg<=64)
    u32 pv = 0;
    if (deg) {
        u32 li = (u32)lane < deg ? (u32)lane : 0u;
        pv = epay[o[0] + li];
    }

    float a0 = 0.f, a1 = 0.f, a2 = 0.f, a3 = 0.f;
#pragma unroll
    for (int r = 0; r < 5; ++r) {              // rel is a compile-time constant
        float adr = adx[r];
        float n0 = 0.f, n1 = 0.f, n2 = 0.f, n3 = 0.f, dsum = 0.f;
        for (u32 e = o[r]; e < o[r + 1]; ++e) {
            u32 i = e - o[0];
            u32 p;
            if (i < 64u) p = __shfl(pv, (int)i);   // wave-uniform condition
            else         p = epay[e];
            float x = as_h[p * 4 + (u32)hd] + adr;
            x = x > 0.f ? x : 0.2f * x;
            float w = __expf(x);
            dsum += w;
            ushort4 hv = *(const ushort4*)(hs + ((size_t)p << 8) + hoff);
            n0 += w * bf2f(hv.x); n1 += w * bf2f(hv.y);
            n2 += w * bf2f(hv.z); n3 += w * bf2f(hv.w);
        }
        float iv = 1.f / (dsum + 1e-16f);      // empty segment: contributes 0, safe
        a0 += n0 * iv; a1 += n1 * iv; a2 += n2 * iv; a3 += n3 * iv;
    }

    float h0 = fmaxf(a0 + bf2f(rr.x) + bb.x, 0.f);
    float h1 = fmaxf(a1 + bf2f(rr.y) + bb.y, 0.f);
    float h2 = fmaxf(a2 + bf2f(rr.z) + bb.z, 0.f);
    float h3 = fmaxf(a3 + bf2f(rr.w) + bb.w, 0.f);
    float s = h0 + h1 + h2 + h3;
    float s2 = h0 * h0 + h1 * h1 + h2 * h2 + h3 * h3;
    for (int o2 = 32; o2; o2 >>= 1) {
        s += __shfl_xor(s, o2);
        s2 += __shfl_xor(s2, o2);
    }
    float mu = s * (1.f / 256.f);
    float var = s2 * (1.f / 256.f) - mu * mu;
    float rs = rsqrtf(var + 1e-5f);
    float4 o4;
    o4.x = (h0 - mu) * rs * g.x + be.x;
    o4.y = (h1 - mu) * rs * g.y + be.y;
    o4.z = (h2 - mu) * rs * g.z + be.z;
    o4.w = (h3 - mu) * rs * g.w + be.w;
    *(float4*)(out + (size_t)row * 256 + c) = o4;
}

// ---------------------------------------------------------------------------
static size_t align256(size_t x) { return (x + 255) & ~(size_t)255; }

extern "C" void kernel_launch(void* const* d_in, const int* in_sizes, int n_in,
                              void* d_out, int out_size, void* d_ws, size_t ws_size,
                              hipStream_t stream) {
    float* out = (float*)d_out;

    int NJ = in_sizes[0] / 128, NS = in_sizes[1] / 128, NM = in_sizes[2] / 128, NR = in_sizes[3] / 128;
    int E = in_sizes[4];
    bool cfg_ok = (n_in >= 21) && (out_size == NJ * 256)
        && (in_sizes[14] == 5 * 128 * 256) && (in_sizes[18] == 128 * 256)
        && (in_sizes[19] == 256) && (in_sizes[20] == 256);
    if (!cfg_ok) { probe_mark<<<8, 256, 0, stream>>>(out, 2048, 1000000.0f); return; }

    const float* x_job = (const float*)d_in[0];
    const float* x_st  = (const float*)d_in[1];
    const float* x_ma  = (const float*)d_in[2];
    const float* x_ro  = (const float*)d_in[3];
    EdgeP EP;
    EP.src[0] = (const int*)d_in[4];  EP.dst[0] = (const int*)d_in[5];
    EP.src[1] = (const int*)d_in[6];  EP.dst[1] = (const int*)d_in[7];
    EP.src[2] = (const int*)d_in[8];  EP.dst[2] = (const int*)d_in[9];
    EP.src[3] = (const int*)d_in[10]; EP.dst[3] = (const int*)d_in[11];
    EP.src[4] = (const int*)d_in[12]; EP.dst[4] = (const int*)d_in[13];
    EP.base[0] = 0; EP.base[1] = NS; EP.base[2] = 2 * NS;
    EP.base[3] = 2 * NS + NM; EP.base[4] = 2 * NS + 2 * NM;
    const float* Ws      = (const float*)d_in[14];
    const float* att_src = (const float*)d_in[15];
    const float* att_dst = (const float*)d_in[16];
    const float* biases  = (const float*)d_in[17];
    const float* W_res   = (const float*)d_in[18];
    const float* gamma   = (const float*)d_in[19];
    const float* beta    = (const float*)d_in[20];

    int nseg = 5 * NJ;
    int nblk = (nseg + 1023) / 1024;
    int NPAD = nblk * 1024;
    int TOT = 2 * NS + 2 * NM + NR;        // concatenated source-node count (hs_cat)
    int TOTX = NJ + NS + NM + NR;          // distinct x rows (xb)

    // --- workspace layout ---
    char* base = (char*)d_ws;
    size_t ob = 0;
    float*  w_d_all  = (float*)(base + ob);  ob += align256(128 * 20 * 4);
    float*  w_s_cat  = (float*)(base + ob);  ob += align256(5 * 128 * 4 * 4);
    float*  bias_sum = (float*)(base + ob);  ob += align256(256 * 4);
    float*  a_d      = (float*)(base + ob);  ob += align256((size_t)NJ * 20 * 4);
    float*  as_cat   = (float*)(base + ob);  ob += align256((size_t)TOT * 4 * 4);
    u16*    wt       = (u16*)(base + ob);    ob += align256((size_t)6 * 256 * 128 * 2);
    u16*    xb       = (u16*)(base + ob);    ob += align256((size_t)TOTX * 128 * 2);
    u16*    resb     = (u16*)(base + ob);    ob += align256((size_t)NJ * 256 * 2);
    u16*    hs_cat   = (u16*)(base + ob);    ob += align256((size_t)TOT * 256 * 2);
    u32*    cnt      = (u32*)(base + ob);    ob += align256((size_t)NPAD * 4);
    u32*    offs     = (u32*)(base + ob);    ob += align256((size_t)NPAD * 4);
    u32*    bsum     = (u32*)(base + ob);    ob += align256((size_t)nblk * 4);
    u32*    epos     = (u32*)(base + ob);    ob += align256((size_t)5 * E * 4);
    u32*    epay     = (u32*)(base + ob);    ob += align256((size_t)5 * E * 4);

    if (ws_size < ob) { probe_mark<<<8, 256, 0, stream>>>(out, 2048, 500000.0f); return; }

    // --- merged prep (zero cnt only, wt, att proj, x->bf16) ---
    int zc = NPAD;
    int nzb = (zc + 255) / 256;
    PrepX PX;
    PX.x[0] = x_job; PX.x[1] = x_st; PX.x[2] = x_ma; PX.x[3] = x_ro;
    PX.rows[0] = NJ; PX.rows[1] = NS; PX.rows[2] = NM; PX.rows[3] = NR;
    u16* xb_job = xb;
    u16* xb_st  = xb + (size_t)NJ * 128;
    u16* xb_ma  = xb + (size_t)(NJ + NS) * 128;
    u16* xb_ro  = xb + (size_t)(NJ + NS + NM) * 128;
    PX.xb[0] = xb_job; PX.xb[1] = xb_st; PX.xb[2] = xb_ma; PX.xb[3] = xb_ro;
    int nxb = 0;
    for (int a = 0; a < 4; ++a) { PX.blks[a] = (PX.rows[a] * 128 + 2047) / 2048; nxb += PX.blks[a]; }
    k_prep_all<<<nzb + 768 + 6 + nxb, 256, 0, stream>>>(Ws, W_res, att_src, att_dst, biases,
                                                        cnt, zc, nzb, wt,
                                                        w_d_all, w_s_cat, bias_sum, PX);

    // --- merged skinny GEMMs v2 (thread = row x 4-col group) ---
    STab ST;
    int st = 0;
    ST.d[0] = {x_job, w_d_all,           a_d,                             NJ, 20, 5, st}; st += NJ * 5;
    ST.d[1] = {x_st,  w_s_cat + 0 * 512, as_cat + (size_t)EP.base[0] * 4, NS, 4, 1, st}; st += NS;
    ST.d[2] = {x_st,  w_s_cat + 1 * 512, as_cat + (size_t)EP.base[1] * 4, NS, 4, 1, st}; st += NS;
    ST.d[3] = {x_ma,  w_s_cat + 2 * 512, as_cat + (size_t)EP.base[2] * 4, NM, 4, 1, st}; st += NM;
    ST.d[4] = {x_ma,  w_s_cat + 3 * 512, as_cat + (size_t)EP.base[3] * 4, NM, 4, 1, st}; st += NM;
    ST.d[5] = {x_ro,  w_s_cat + 4 * 512, as_cat + (size_t)EP.base[4] * 4, NR, 4, 1, st}; st += NR;
    ST.total = st;
    skinny_all<<<(ST.total + 255) / 256, 256, 0, stream>>>(ST);

    // --- merged MFMA GEMMs (1-D grid; strip loop inside, A staged once) ---
    int tJ = (NJ + 63) / 64, tS = (NS + 63) / 64, tM = (NM + 63) / 64, tR = (NR + 63) / 64;
    GTab GT;
    int gs = 0;
    GT.d[0] = {xb_job, resb,                              5, NJ, gs}; gs += tJ;
    GT.d[1] = {xb_st,  hs_cat + (size_t)EP.base[0] * 256, 0, NS, gs}; gs += tS;
    GT.d[2] = {xb_st,  hs_cat + (size_t)EP.base[1] * 256, 1, NS, gs}; gs += tS;
    GT.d[3] = {xb_ma,  hs_cat + (size_t)EP.base[2] * 256, 2, NM, gs}; gs += tM;
    GT.d[4] = {xb_ma,  hs_cat + (size_t)EP.base[3] * 256, 3, NM, gs}; gs += tM;
    GT.d[5] = {xb_ro,  hs_cat + (size_t)EP.base[4] * 256, 4, NR, gs}; gs += tR;
    gemm_all<<<gs, 256, 0, stream>>>(GT, wt);

    // --- (row,rel)-segmented CSR build (atomic-free fill via recorded positions) ---
    k_count<<<dim3((E + 255) / 256, 5), 256, 0, stream>>>(EP, cnt, epos, E);
    k_scan1<<<nblk, 256, 0, stream>>>(cnt, offs, bsum, nblk);
    k_scan23<<<nblk, 256, 0, stream>>>(offs, bsum, nblk);
    k_fill<<<dim3((E + 255) / 256, 5), 256, 0, stream>>>(EP, offs, epos, epay, E);

    // --- fused denominators + gather + residual + ReLU + LN (single launch, frozen) ---
    k_gather<<<(NJ + 7) / 8, 512, 0, stream>>>(offs, epay, as_cat,
                                               a_d, hs_cat, resb, bias_sum,
                                               gamma, beta, out, NJ);
}

// Round 14
// 489.995 us; speedup vs baseline: 1.1822x; 1.0796x over previous
//
#include <hip/hip_runtime.h>

typedef unsigned short u16;
typedef unsigned int u32;
typedef unsigned long long u64;
typedef __attribute__((ext_vector_type(8))) short s16x8;   // 8 bf16 (4 VGPRs)
typedef __attribute__((ext_vector_type(4))) float f32x4;

__device__ __forceinline__ float bf2f(u16 u) { return __uint_as_float(((u32)u) << 16); }
__device__ __forceinline__ u16 f2bf(float f) {
    u32 b = __float_as_uint(f);
    b += 0x7fffu + ((b >> 16) & 1u);
    return (u16)(b >> 16);
}

__global__ void probe_mark(float* __restrict__ out, int n, float val) {
    int i = blockIdx.x * blockDim.x + threadIdx.x;
    if (i < n) out[i] = val;
}

// ---------------- merged prep: zero cnt + wt convert + att proj + x->bf16 convert ------------
struct PrepX { const float* x[4]; int rows[4]; int blks[4]; u16* xb[4]; };

__global__ void k_prep_all(const float* __restrict__ Ws, const float* __restrict__ W_res,
                           const float* __restrict__ att_src, const float* __restrict__ att_dst,
                           const float* __restrict__ biases,
                           u32* __restrict__ cnt, int zc, int nzb, u16* __restrict__ wt,
                           float* __restrict__ w_d_all, float* __restrict__ w_s_cat,
                           float* __restrict__ bias_sum, PrepX PX) {
    int b = blockIdx.x;
    if (b < nzb) {
        int i = b * 256 + threadIdx.x;
        if (i < zc) cnt[i] = 0u;
        return;
    }
    b -= nzb;
    if (b < 768) {                      // 768*256 == 6*256*128 exactly
        int i = b * 256 + threadIdx.x;
        int k = i & 127;
        int c = (i >> 7) & 255;
        int w = i >> 15;
        float v = (w < 5) ? Ws[(size_t)w * 32768 + k * 256 + c] : W_res[k * 256 + c];
        wt[i] = f2bf(v);
        return;
    }
    b -= 768;
    if (b < 6) {
        if (b < 5) {
            int k = threadIdx.x;
            if (k >= 128) return;
            const float* Wr = Ws + (size_t)b * 128 * 256 + (size_t)k * 256;
            for (int h = 0; h < 4; ++h) {
                float ss = 0.f, sd = 0.f;
                for (int c = 0; c < 64; ++c) {
                    float w = Wr[h * 64 + c];
                    ss += w * att_src[(b * 4 + h) * 64 + c];
                    sd += w * att_dst[(b * 4 + h) * 64 + c];
                }
                w_d_all[k * 20 + b * 4 + h] = sd;
                w_s_cat[b * 512 + k * 4 + h] = ss;
            }
        } else if (threadIdx.x < 256) {
            float s = 0.f;
            for (int r = 0; r < 5; ++r) s += biases[r * 256 + threadIdx.x];
            bias_sum[threadIdx.x] = s;
        }
        return;
    }
    b -= 6;
    // xb convert: 256 threads x 8 elems = 2048 fp32/block per sub-region
#pragma unroll
    for (int a = 0; a < 4; ++a) {
        if (b < PX.blks[a]) {
            int elem = b * 2048 + threadIdx.x * 8;
            if (elem < PX.rows[a] * 128) {          // elem%8==0, tot%8==0 -> full chunk
                const float4* src = (const float4*)(PX.x[a] + elem);
                float4 v0 = src[0], v1 = src[1];
                u32 w0 = ((u32)f2bf(v0.y) << 16) | f2bf(v0.x);
                u32 w1 = ((u32)f2bf(v0.w) << 16) | f2bf(v0.z);
                u32 w2 = ((u32)f2bf(v1.y) << 16) | f2bf(v1.x);
                u32 w3 = ((u32)f2bf(v1.w) << 16) | f2bf(v1.z);
                *(uint4*)(PX.xb[a] + elem) = make_uint4(w0, w1, w2, w3);
            }
            return;
        }
        b -= PX.blks[a];
    }
}

// ---------------- mid mega-kernel: gemm + skinny + count co-scheduled ----------------
// R12/R13 PMC: k_count/k_fill are latency-bound (VALUBusy 0.6%) while gemm/skinny are
// compute/BW-bound; serialized they waste the overlap. All three are independent (disjoint
// in/out, all depend only on prep). One launch, roles interleaved per 11-block stripe
// (3 gemm / 5 count / 3 skinny = proportional to 2582:4885:2207 block counts) so stalled
// count waves co-reside with busy gemm waves on each CU.
struct SDesc { const float* A; const float* W; float* out; int N; int Kout; int groups; int start; };
struct STab { SDesc d[6]; int total; };
struct GDesc { const u16* A; u16* C; int wslice; int N; int start; };
struct GTab { GDesc d[6]; };
struct EdgeP { const int* src[5]; const int* dst[5]; int base[5]; };

__global__ __launch_bounds__(256) void k_mid(GTab T, const u16* __restrict__ wt,
                                             STab S, EdgeP P,
                                             u32* __restrict__ cnt, u32* __restrict__ epos,
                                             int E, int nEB, int G, int C, int SB) {
    __shared__ __align__(16) u16 sA[64][136];
    __shared__ __align__(16) u16 sB[64][136];
    int q = blockIdx.x / 11, p = blockIdx.x % 11;
    int t = threadIdx.x;

    if (p < 3) {                       // ---- gemm role ----
        int bx = q * 3 + p;
        if (bx >= G) return;
        int mi = 0;
#pragma unroll
        for (int i = 1; i < 6; ++i) if (bx >= T.d[i].start) mi = i;
        GDesc d = T.d[mi];
        int R0 = (bx - d.start) * 64;
        int r = t >> 2, seg = (t & 3) * 32;
        {   // stage A once (bf16 direct)
            uint4 a0, a1, a2, a3;
            if (R0 + r < d.N) {
                const uint4* pa = (const uint4*)(d.A + (size_t)(R0 + r) * 128 + seg);
                a0 = pa[0]; a1 = pa[1]; a2 = pa[2]; a3 = pa[3];
            } else {
                a0 = a1 = a2 = a3 = make_uint4(0, 0, 0, 0);
            }
            uint4* qd = (uint4*)&sA[r][seg];
            qd[0] = a0; qd[1] = a1; qd[2] = a2; qd[3] = a3;
        }
        int wave = t >> 6, lane = t & 63;
        int quad = lane >> 4, m = lane & 15;
        const u16* aRow = &sA[wave * 16 + m][0];
        const u16* wbase = wt + (size_t)d.wslice * 32768;

        for (int y = 0; y < 4; ++y) {
            int c0 = y * 64;
            const uint4* pb = (const uint4*)(wbase + (size_t)(c0 + r) * 128 + seg);
            uint4 b0 = pb[0], b1 = pb[1], b2 = pb[2], b3 = pb[3];
            __syncthreads();
            uint4* qb = (uint4*)&sB[r][seg];
            qb[0] = b0; qb[1] = b1; qb[2] = b2; qb[3] = b3;
            __syncthreads();

            f32x4 acc[4] = {};
#pragma unroll
            for (int k0 = 0; k0 < 128; k0 += 32) {
                s16x8 af = *(const s16x8*)(aRow + k0 + quad * 8);
#pragma unroll
                for (int ct = 0; ct < 4; ++ct) {
                    s16x8 bf = *(const s16x8*)(&sB[ct * 16 + m][k0 + quad * 8]);
                    acc[ct] = __builtin_amdgcn_mfma_f32_16x16x32_bf16(af, bf, acc[ct], 0, 0, 0);
                }
            }
#pragma unroll
            for (int ct = 0; ct < 4; ++ct) {
#pragma unroll
                for (int i = 0; i < 4; ++i) {
                    int row = R0 + wave * 16 + quad * 4 + i;
                    if (row < d.N) d.C[(size_t)row * 256 + c0 + ct * 16 + m] = f2bf(acc[ct][i]);
                }
            }
        }
    } else if (p < 8) {                // ---- count role ----
        int i = q * 5 + (p - 3);
        if (i >= C) return;
        int r = i / nEB, eb = i - r * nEB;
        int e = eb * 256 + t;
        if (e >= E) return;
        u32 c = atomicAdd(cnt + (size_t)P.dst[r][e] * 5 + r, 1u);
        epos[(size_t)r * E + e] = c;
    } else {                           // ---- skinny role ----
        int i = q * 3 + (p - 8);
        if (i >= SB) return;
        int idx = i * 256 + t;
        if (idx >= S.total) return;
        int mi = 0;
#pragma unroll
        for (int j = 1; j < 6; ++j) if (idx >= S.d[j].start) mi = j;
        SDesc d = S.d[mi];
        int local = idx - d.start;
        int row = local / d.groups, g = local - row * d.groups;
        const float* a = d.A + (size_t)row * 128;
        const float* w = d.W + g * 4;
        int Kout = d.Kout;
        float s0 = 0.f, s1 = 0.f, s2 = 0.f, s3 = 0.f;
        for (int k = 0; k < 128; k += 4) {
            float4 av = *(const float4*)(a + k);
            float4 w0 = *(const float4*)(w + (size_t)(k + 0) * Kout);
            float4 w1 = *(const float4*)(w + (size_t)(k + 1) * Kout);
            float4 w2 = *(const float4*)(w + (size_t)(k + 2) * Kout);
            float4 w3 = *(const float4*)(w + (size_t)(k + 3) * Kout);
            s0 += av.x * w0.x + av.y * w1.x + av.z * w2.x + av.w * w3.x;
            s1 += av.x * w0.y + av.y * w1.y + av.z * w2.y + av.w * w3.y;
            s2 += av.x * w0.z + av.y * w1.z + av.z * w2.z + av.w * w3.z;
            s3 += av.x * w0.w + av.y * w1.w + av.z * w2.w + av.w * w3.w;
        }
        float* o = d.out + (size_t)row * Kout + g * 4;
        *(float4*)o = make_float4(s0, s1, s2, s3);
    }
}

// ---------------- CSR scans + atomic-free fill (R13, proven) ----------------
__global__ void k_scan1(const u32* __restrict__ cnt, u32* __restrict__ off,
                        u32* __restrict__ bsum, int nblk) {
    int b = blockIdx.x, t = threadIdx.x;
    size_t base = (size_t)b * 1024 + t * 4;
    u32 v0 = cnt[base], v1 = cnt[base + 1], v2 = cnt[base + 2], v3 = cnt[base + 3];
    u32 tsum = v0 + v1 + v2 + v3;
    __shared__ u32 s[256];
    u32 x = tsum;
    s[t] = x; __syncthreads();
    for (int ofs = 1; ofs < 256; ofs <<= 1) {
        u32 y = (t >= ofs) ? s[t - ofs] : 0u;
        __syncthreads();
        x += y; s[t] = x;
        __syncthreads();
    }
    u32 ex = x - tsum;
    off[base] = ex; off[base + 1] = ex + v0; off[base + 2] = ex + v0 + v1; off[base + 3] = ex + v0 + v1 + v2;
    if (t == 255) bsum[b] = x;
}

__global__ void k_scan23(u32* __restrict__ off, const u32* __restrict__ bsum, int nblk) {
    int b = blockIdx.x, t = threadIdx.x;   // 256 threads
    __shared__ u32 s[256];
    u32 part = 0;
    for (int i = t; i < b; i += 256) part += bsum[i];
    s[t] = part; __syncthreads();
    for (int ofs = 128; ofs; ofs >>= 1) {
        if (t < ofs) s[t] += s[t + ofs];
        __syncthreads();
    }
    u32 add = s[0];
    size_t base = (size_t)b * 1024 + t * 4;
    off[base] += add; off[base + 1] += add; off[base + 2] += add; off[base + 3] += add;
}

__global__ void k_fill(EdgeP P, const u32* __restrict__ off, const u32* __restrict__ epos,
                       u32* __restrict__ epay, int E) {
    int r = blockIdx.y;
    int e = blockIdx.x * blockDim.x + threadIdx.x;
    if (e >= E) return;
    int d = P.dst[r][e];
    u32 pos = off[(size_t)d * 5 + r] + epos[(size_t)r * E + e];
    epay[pos] = (u32)(P.base[r] + P.src[r][e]);
}

// ---------------- fused gather — R9/R11 version (best measured ~164us), FROZEN -----------
__global__ __launch_bounds__(512) void k_gather(
        const u32* __restrict__ offs, const u32* __restrict__ epay,
        const float* __restrict__ as_h,   // as_cat: [gsrc][4 heads]
        const float* __restrict__ a_d,    // [row][rel*4+h]
        const u16* __restrict__ hs, const u16* __restrict__ resb,
        const float* __restrict__ bias_sum,
        const float* __restrict__ gamma, const float* __restrict__ beta,
        float* __restrict__ out, int NJ) {
    int row = blockIdx.x * 8 + (threadIdx.x >> 6);
    int lane = threadIdx.x & 63;
    if (row >= NJ) return;

    // hoisted epilogue loads — hide under the gather
    ushort4 rr = *(const ushort4*)(resb + (size_t)row * 256 + lane * 4);
    float4 bb = *(const float4*)(bias_sum + lane * 4);
    int c = lane * 4;
    float4 g = *(const float4*)(gamma + c);
    float4 be = *(const float4*)(beta + c);

    int hd = lane >> 4;                        // this lane's head (0..3)
    u32 hoff = (u32)(lane << 2);               // u16-elem offset within an hs row

    const float* adb = a_d + (size_t)row * 20 + hd;
    float adx[5] = { adb[0], adb[4], adb[8], adb[12], adb[16] };

    const u32* op = offs + (size_t)row * 5;
    u32 o[6];
#pragma unroll
    for (int i = 0; i < 6; ++i) o[i] = op[i];
    u32 deg = o[5] - o[0];

    // cooperative payload preload: lane L holds epay[o0+L] (covers rows with deg<=64)
    u32 pv = 0;
    if (deg) {
        u32 li = (u32)lane < deg ? (u32)lane : 0u;
        pv = epay[o[0] + li];
    }

    float a0 = 0.f, a1 = 0.f, a2 = 0.f, a3 = 0.f;
#pragma unroll
    for (int r = 0; r < 5; ++r) {              // rel is a compile-time constant
        float adr = adx[r];
        float n0 = 0.f, n1 = 0.f, n2 = 0.f, n3 = 0.f, dsum = 0.f;
        for (u32 e = o[r]; e < o[r + 1]; ++e) {
            u32 i = e - o[0];
            u32 p;
            if (i < 64u) p = __shfl(pv, (int)i);   // wave-uniform condition
            else         p = epay[e];
            float x = as_h[p * 4 + (u32)hd] + adr;
            x = x > 0.f ? x : 0.2f * x;
            float w = __expf(x);
            dsum += w;
            ushort4 hv = *(const ushort4*)(hs + ((size_t)p << 8) + hoff);
            n0 += w * bf2f(hv.x); n1 += w * bf2f(hv.y);
            n2 += w * bf2f(hv.z); n3 += w * bf2f(hv.w);
        }
        float iv = 1.f / (dsum + 1e-16f);      // empty segment: contributes 0, safe
        a0 += n0 * iv; a1 += n1 * iv; a2 += n2 * iv; a3 += n3 * iv;
    }

    float h0 = fmaxf(a0 + bf2f(rr.x) + bb.x, 0.f);
    float h1 = fmaxf(a1 + bf2f(rr.y) + bb.y, 0.f);
    float h2 = fmaxf(a2 + bf2f(rr.z) + bb.z, 0.f);
    float h3 = fmaxf(a3 + bf2f(rr.w) + bb.w, 0.f);
    float s = h0 + h1 + h2 + h3;
    float s2 = h0 * h0 + h1 * h1 + h2 * h2 + h3 * h3;
    for (int o2 = 32; o2; o2 >>= 1) {
        s += __shfl_xor(s, o2);
        s2 += __shfl_xor(s2, o2);
    }
    float mu = s * (1.f / 256.f);
    float var = s2 * (1.f / 256.f) - mu * mu;
    float rs = rsqrtf(var + 1e-5f);
    float4 o4;
    o4.x = (h0 - mu) * rs * g.x + be.x;
    o4.y = (h1 - mu) * rs * g.y + be.y;
    o4.z = (h2 - mu) * rs * g.z + be.z;
    o4.w = (h3 - mu) * rs * g.w + be.w;
    *(float4*)(out + (size_t)row * 256 + c) = o4;
}

// ---------------------------------------------------------------------------
static size_t align256(size_t x) { return (x + 255) & ~(size_t)255; }

extern "C" void kernel_launch(void* const* d_in, const int* in_sizes, int n_in,
                              void* d_out, int out_size, void* d_ws, size_t ws_size,
                              hipStream_t stream) {
    float* out = (float*)d_out;

    int NJ = in_sizes[0] / 128, NS = in_sizes[1] / 128, NM = in_sizes[2] / 128, NR = in_sizes[3] / 128;
    int E = in_sizes[4];
    bool cfg_ok = (n_in >= 21) && (out_size == NJ * 256)
        && (in_sizes[14] == 5 * 128 * 256) && (in_sizes[18] == 128 * 256)
        && (in_sizes[19] == 256) && (in_sizes[20] == 256);
    if (!cfg_ok) { probe_mark<<<8, 256, 0, stream>>>(out, 2048, 1000000.0f); return; }

    const float* x_job = (const float*)d_in[0];
    const float* x_st  = (const float*)d_in[1];
    const float* x_ma  = (const float*)d_in[2];
    const float* x_ro  = (const float*)d_in[3];
    EdgeP EP;
    EP.src[0] = (const int*)d_in[4];  EP.dst[0] = (const int*)d_in[5];
    EP.src[1] = (const int*)d_in[6];  EP.dst[1] = (const int*)d_in[7];
    EP.src[2] = (const int*)d_in[8];  EP.dst[2] = (const int*)d_in[9];
    EP.src[3] = (const int*)d_in[10]; EP.dst[3] = (const int*)d_in[11];
    EP.src[4] = (const int*)d_in[12]; EP.dst[4] = (const int*)d_in[13];
    EP.base[0] = 0; EP.base[1] = NS; EP.base[2] = 2 * NS;
    EP.base[3] = 2 * NS + NM; EP.base[4] = 2 * NS + 2 * NM;
    const float* Ws      = (const float*)d_in[14];
    const float* att_src = (const float*)d_in[15];
    const float* att_dst = (const float*)d_in[16];
    const float* biases  = (const float*)d_in[17];
    const float* W_res   = (const float*)d_in[18];
    const float* gamma   = (const float*)d_in[19];
    const float* beta    = (const float*)d_in[20];

    int nseg = 5 * NJ;
    int nblk = (nseg + 1023) / 1024;
    int NPAD = nblk * 1024;
    int TOT = 2 * NS + 2 * NM + NR;        // concatenated source-node count (hs_cat)
    int TOTX = NJ + NS + NM + NR;          // distinct x rows (xb)

    // --- workspace layout ---
    char* base = (char*)d_ws;
    size_t ob = 0;
    float*  w_d_all  = (float*)(base + ob);  ob += align256(128 * 20 * 4);
    float*  w_s_cat  = (float*)(base + ob);  ob += align256(5 * 128 * 4 * 4);
    float*  bias_sum = (float*)(base + ob);  ob += align256(256 * 4);
    float*  a_d      = (float*)(base + ob);  ob += align256((size_t)NJ * 20 * 4);
    float*  as_cat   = (float*)(base + ob);  ob += align256((size_t)TOT * 4 * 4);
    u16*    wt       = (u16*)(base + ob);    ob += align256((size_t)6 * 256 * 128 * 2);
    u16*    xb       = (u16*)(base + ob);    ob += align256((size_t)TOTX * 128 * 2);
    u16*    resb     = (u16*)(base + ob);    ob += align256((size_t)NJ * 256 * 2);
    u16*    hs_cat   = (u16*)(base + ob);    ob += align256((size_t)TOT * 256 * 2);
    u32*    cnt      = (u32*)(base + ob);    ob += align256((size_t)NPAD * 4);
    u32*    offs     = (u32*)(base + ob);    ob += align256((size_t)NPAD * 4);
    u32*    bsum     = (u32*)(base + ob);    ob += align256((size_t)nblk * 4);
    u32*    epos     = (u32*)(base + ob);    ob += align256((size_t)5 * E * 4);
    u32*    epay     = (u32*)(base + ob);    ob += align256((size_t)5 * E * 4);

    if (ws_size < ob) { probe_mark<<<8, 256, 0, stream>>>(out, 2048, 500000.0f); return; }

    // --- merged prep (zero cnt, wt, att proj, x->bf16) ---
    int zc = NPAD;
    int nzb = (zc + 255) / 256;
    PrepX PX;
    PX.x[0] = x_job; PX.x[1] = x_st; PX.x[2] = x_ma; PX.x[3] = x_ro;
    PX.rows[0] = NJ; PX.rows[1] = NS; PX.rows[2] = NM; PX.rows[3] = NR;
    u16* xb_job = xb;
    u16* xb_st  = xb + (size_t)NJ * 128;
    u16* xb_ma  = xb + (size_t)(NJ + NS) * 128;
    u16* xb_ro  = xb + (size_t)(NJ + NS + NM) * 128;
    PX.xb[0] = xb_job; PX.xb[1] = xb_st; PX.xb[2] = xb_ma; PX.xb[3] = xb_ro;
    int nxb = 0;
    for (int a = 0; a < 4; ++a) { PX.blks[a] = (PX.rows[a] * 128 + 2047) / 2048; nxb += PX.blks[a]; }
    k_prep_all<<<nzb + 768 + 6 + nxb, 256, 0, stream>>>(Ws, W_res, att_src, att_dst, biases,
                                                        cnt, zc, nzb, wt,
                                                        w_d_all, w_s_cat, bias_sum, PX);

    // --- mid mega-kernel: gemm + count + skinny co-scheduled ---
    STab ST;
    int st = 0;
    ST.d[0] = {x_job, w_d_all,           a_d,                             NJ, 20, 5, st}; st += NJ * 5;
    ST.d[1] = {x_st,  w_s_cat + 0 * 512, as_cat + (size_t)EP.base[0] * 4, NS, 4, 1, st}; st += NS;
    ST.d[2] = {x_st,  w_s_cat + 1 * 512, as_cat + (size_t)EP.base[1] * 4, NS, 4, 1, st}; st += NS;
    ST.d[3] = {x_ma,  w_s_cat + 2 * 512, as_cat + (size_t)EP.base[2] * 4, NM, 4, 1, st}; st += NM;
    ST.d[4] = {x_ma,  w_s_cat + 3 * 512, as_cat + (size_t)EP.base[3] * 4, NM, 4, 1, st}; st += NM;
    ST.d[5] = {x_ro,  w_s_cat + 4 * 512, as_cat + (size_t)EP.base[4] * 4, NR, 4, 1, st}; st += NR;
    ST.total = st;

    int tJ = (NJ + 63) / 64, tS = (NS + 63) / 64, tM = (NM + 63) / 64, tR = (NR + 63) / 64;
    GTab GT;
    int gs = 0;
    GT.d[0] = {xb_job, resb,                              5, NJ, gs}; gs += tJ;
    GT.d[1] = {xb_st,  hs_cat + (size_t)EP.base[0] * 256, 0, NS, gs}; gs += tS;
    GT.d[2] = {xb_st,  hs_cat + (size_t)EP.base[1] * 256, 1, NS, gs}; gs += tS;
    GT.d[3] = {xb_ma,  hs_cat + (size_t)EP.base[2] * 256, 2, NM, gs}; gs += tM;
    GT.d[4] = {xb_ma,  hs_cat + (size_t)EP.base[3] * 256, 3, NM, gs}; gs += tM;
    GT.d[5] = {xb_ro,  hs_cat + (size_t)EP.base[4] * 256, 4, NR, gs}; gs += tR;

    int nEB = (E + 255) / 256;
    int G = gs, C = 5 * nEB, SB = (ST.total + 255) / 256;
    int stripes = (G + 2) / 3;
    if ((C + 4) / 5 > stripes) stripes = (C + 4) / 5;
    if ((SB + 2) / 3 > stripes) stripes = (SB + 2) / 3;
    k_mid<<<stripes * 11, 256, 0, stream>>>(GT, wt, ST, EP, cnt, epos, E, nEB, G, C, SB);

    // --- CSR scans + atomic-free fill ---
    k_scan1<<<nblk, 256, 0, stream>>>(cnt, offs, bsum, nblk);
    k_scan23<<<nblk, 256, 0, stream>>>(offs, bsum, nblk);
    k_fill<<<dim3(nEB, 5), 256, 0, stream>>>(EP, offs, epos, epay, E);

    // --- fused denominators + gather + residual + ReLU + LN (frozen) ---
    k_gather<<<(NJ + 7) / 8, 512, 0, stream>>>(offs, epay, as_cat,
                                               a_d, hs_cat, resb, bias_sum,
                                               gamma, beta, out, NJ);
}